// Round 1
// 363.925 us; speedup vs baseline: 1.0191x; 1.0191x over previous
//
#include <hip/hip_runtime.h>

// Embedding gather: out[i, :] = table[indices[i], :]
// VOCAB = 1,000,000 rows, EMBED_DIM = 16 floats (64 B) per row,
// NUM_INDICES = 4,194,304.
//
// Layout: one thread per float4 (16 B) of output -> 4 threads/row.
// Consecutive lanes write consecutive float4s => fully coalesced 1 KB/wave
// stores. The 4 lanes of a row broadcast-read the same index and a
// contiguous 64 B table row.
//
// Round-1 change: cache-policy hints.
//  - Output (256 MiB/launch, written once, never re-read) and indices
//    (16 MiB, read once) are STREAMING -> nontemporal, so they do not
//    allocate in / sweep the 256 MB Infinity Cache.
//  - Table (64 MB) stays on the default cached path -> remains L3-resident,
//    so the random 64 B gather is served from cache instead of
//    random-granularity HBM reads (which were the 370 us bottleneck).

typedef float v4f __attribute__((ext_vector_type(4)));

__global__ void __launch_bounds__(256)
embed_gather_kernel(const int* __restrict__ indices,
                    const v4f* __restrict__ table4,
                    v4f* __restrict__ out4,
                    int n_rows) {
    int t = blockIdx.x * blockDim.x + threadIdx.x;
    int row = t >> 2;   // which index
    int seg = t & 3;    // which float4 within the 16-float row
    if (row < n_rows) {
        // streamed once: don't pollute L2/L3
        int r = __builtin_nontemporal_load(indices + row);
        // hot, reused ~4.2x, 64 MB -> keep cached (L3-resident)
        v4f v = table4[(size_t)r * 4 + seg];
        // pure write stream: bypass cache allocation
        __builtin_nontemporal_store(v, out4 + t);
    }
}

extern "C" void kernel_launch(void* const* d_in, const int* in_sizes, int n_in,
                              void* d_out, int out_size, void* d_ws, size_t ws_size,
                              hipStream_t stream) {
    const int* indices = (const int*)d_in[0];
    const v4f* table4  = (const v4f*)d_in[1];
    v4f*       out4    = (v4f*)d_out;

    int n_rows = in_sizes[0];                          // 4,194,304
    long long total_threads = (long long)n_rows * 4;   // one float4 each
    int block = 256;
    int grid = (int)((total_threads + block - 1) / block);

    embed_gather_kernel<<<grid, block, 0, stream>>>(indices, table4, out4, n_rows);
}